// Round 3
// baseline (757.008 us; speedup 1.0000x reference)
//
#include <hip/hip_runtime.h>
#include <hip/hip_bf16.h>
#include <cstdint>

// B=4, S=1024, E=1024, H=16, D=64.
// Contract (per harness doc): inputs are fp32 (reference dtype), d_out is fp32:
//   d_out = [ out (4M floats) | filtered_attn (64M floats) ].
// Internally: bf16 MFMA; split-bf16 (hi+lo, 3 MFMAs) for the q/k path so the
// logits are near-fp32 accurate (minimizes p>4e-4 selection flips vs np ref).

#define BB 4
#define SS 1024
#define EE 1024
#define HH 16
#define DD 64

typedef __attribute__((ext_vector_type(8))) short bf16x8;
typedef __attribute__((ext_vector_type(4))) float f32x4;

// ---------------------------------------------------------------------------
// split cast: hi = bf16(v), lo = bf16(v - hi). lo may be null (plain cast).
// ---------------------------------------------------------------------------
__global__ __launch_bounds__(256) void split_f32(
    const float* __restrict__ in, __hip_bfloat16* __restrict__ hi,
    __hip_bfloat16* __restrict__ lo, int n4) {
  int i = blockIdx.x * 256 + threadIdx.x;
  if (i >= n4) return;
  float4 v = ((const float4*)in)[i];
  float vv[4] = {v.x, v.y, v.z, v.w};
  __hip_bfloat16 h[4], l[4];
#pragma unroll
  for (int j = 0; j < 4; ++j) {
    h[j] = __float2bfloat16(vv[j]);
    l[j] = __float2bfloat16(vv[j] - __bfloat162float(h[j]));
  }
  ((ushort4*)hi)[i] = *(ushort4*)h;
  if (lo) ((ushort4*)lo)[i] = *(ushort4*)l;
}

// ---------------------------------------------------------------------------
// NT GEMM: C[m][n] = sum_k A[m*lda+k]*B[n*ldb+k]. 128x128 tile, BK=64,
// 4 waves (2x2), 4x4 x 16x16x32 bf16 MFMA per wave.
// MODE 0 (SPLIT): A=(xh,xl) B=(Wqh,Wql); +bias(f32); out: qh,ql,kh,kl [B,H,S,D], vT [B,H,D,S]
// MODE 1 (SPLIT): A=(qh,ql) B=(kh,kl); out fp32 logits*0.125 -> oF + z*S*S
// MODE 2 (A fp32): A=filtered_attn(f32, cvt in staging) B=vT; out ao bf16 [B*S,E]
// MODE 3: A=ao B=Wproj_h; +bias(f32); out fp32 oF[m*E+n]
// ---------------------------------------------------------------------------
template <int MODE>
__global__ __launch_bounds__(256) void gemm(
    const __hip_bfloat16* __restrict__ Ah, const __hip_bfloat16* __restrict__ Al,
    const __hip_bfloat16* __restrict__ Bh, const __hip_bfloat16* __restrict__ Bl,
    const float* __restrict__ Af, const float* __restrict__ bias,
    float* __restrict__ oF, __hip_bfloat16* __restrict__ o1,
    __hip_bfloat16* __restrict__ o2, __hip_bfloat16* __restrict__ o3,
    __hip_bfloat16* __restrict__ o4, __hip_bfloat16* __restrict__ o5,
    int M, int N, int K, int lda, int ldb, long long sA, long long sB) {
  constexpr bool SPLIT = (MODE == 0 || MODE == 1);
  constexpr bool AF32  = (MODE == 2);

  const int tid  = threadIdx.x;
  const int lane = tid & 63;
  const int wave = tid >> 6;
  const int wm   = (wave >> 1) * 64;
  const int wn   = (wave & 1) * 64;
  const int quad = lane >> 4;
  const int l15  = lane & 15;
  const int m0   = blockIdx.y * 128;
  const int n0   = blockIdx.x * 128;
  const long long zz = blockIdx.z;

  if (AF32) Af += zz * sA;
  else { Ah += zz * sA; if (SPLIT) Al += zz * sA; }
  Bh += zz * sB;
  if (SPLIT) Bl += zz * sB;

  __shared__ __align__(16) __hip_bfloat16 lds[(SPLIT ? 4 : 2) * 128 * 72];
  __hip_bfloat16* lAh = lds;
  __hip_bfloat16* lAl = SPLIT ? lds + 128 * 72 : nullptr;
  __hip_bfloat16* lBh = lds + (SPLIT ? 2 : 1) * 128 * 72;
  __hip_bfloat16* lBl = SPLIT ? lds + 3 * 128 * 72 : nullptr;

  f32x4 acc[4][4] = {};

  for (int k0 = 0; k0 < K; k0 += 64) {
#pragma unroll
    for (int it = 0; it < 4; ++it) {
      int flat = (it * 256 + tid) * 8;
      int row  = flat >> 6;
      int kk   = flat & 63;
      const bool mok = (m0 + row < M);
      const bool nok = (n0 + row < N);
      if (AF32) {
        float4 f0 = {0, 0, 0, 0}, f1 = {0, 0, 0, 0};
        if (mok) {
          const float* src = Af + (long long)(m0 + row) * lda + k0 + kk;
          f0 = *(const float4*)src;
          f1 = *(const float4*)(src + 4);
        }
        __hip_bfloat16 t[8];
        t[0] = __float2bfloat16(f0.x); t[1] = __float2bfloat16(f0.y);
        t[2] = __float2bfloat16(f0.z); t[3] = __float2bfloat16(f0.w);
        t[4] = __float2bfloat16(f1.x); t[5] = __float2bfloat16(f1.y);
        t[6] = __float2bfloat16(f1.z); t[7] = __float2bfloat16(f1.w);
        *(uint4*)&lAh[row * 72 + kk] = *(uint4*)t;
      } else {
        uint4 va = {0, 0, 0, 0};
        if (mok) va = *(const uint4*)(Ah + (long long)(m0 + row) * lda + k0 + kk);
        *(uint4*)&lAh[row * 72 + kk] = va;
        if (SPLIT) {
          uint4 vl = {0, 0, 0, 0};
          if (mok) vl = *(const uint4*)(Al + (long long)(m0 + row) * lda + k0 + kk);
          *(uint4*)&lAl[row * 72 + kk] = vl;
        }
      }
      uint4 vb = {0, 0, 0, 0};
      if (nok) vb = *(const uint4*)(Bh + (long long)(n0 + row) * ldb + k0 + kk);
      *(uint4*)&lBh[row * 72 + kk] = vb;
      if (SPLIT) {
        uint4 vbl = {0, 0, 0, 0};
        if (nok) vbl = *(const uint4*)(Bl + (long long)(n0 + row) * ldb + k0 + kk);
        *(uint4*)&lBl[row * 72 + kk] = vbl;
      }
    }
    __syncthreads();

#pragma unroll
    for (int ks = 0; ks < 64; ks += 32) {
      bf16x8 ah[4], bh[4], al[4], bl[4];
#pragma unroll
      for (int i = 0; i < 4; ++i) {
        int off = (wm + i * 16 + l15) * 72 + ks + quad * 8;
        ah[i] = *(const bf16x8*)&lAh[off];
        if (SPLIT) al[i] = *(const bf16x8*)&lAl[off];
      }
#pragma unroll
      for (int j = 0; j < 4; ++j) {
        int off = (wn + j * 16 + l15) * 72 + ks + quad * 8;
        bh[j] = *(const bf16x8*)&lBh[off];
        if (SPLIT) bl[j] = *(const bf16x8*)&lBl[off];
      }
#pragma unroll
      for (int i = 0; i < 4; ++i)
#pragma unroll
        for (int j = 0; j < 4; ++j) {
          if (SPLIT) {
            acc[i][j] = __builtin_amdgcn_mfma_f32_16x16x32_bf16(al[i], bh[j], acc[i][j], 0, 0, 0);
            acc[i][j] = __builtin_amdgcn_mfma_f32_16x16x32_bf16(ah[i], bl[j], acc[i][j], 0, 0, 0);
          }
          acc[i][j] = __builtin_amdgcn_mfma_f32_16x16x32_bf16(ah[i], bh[j], acc[i][j], 0, 0, 0);
        }
    }
    __syncthreads();
  }

  // C/D layout: col = lane&15, row = quad*4 + reg
#pragma unroll
  for (int i = 0; i < 4; ++i) {
#pragma unroll
    for (int j = 0; j < 4; ++j) {
#pragma unroll
      for (int r = 0; r < 4; ++r) {
        int m = m0 + wm + i * 16 + quad * 4 + r;
        int n = n0 + wn + j * 16 + l15;
        float v = acc[i][j][r];
        if (MODE == 0) {
          v += bias[n];
          int c = n >> 10, nn = n & 1023, h = nn >> 6, d = nn & 63;
          int b = m >> 10, s = m & 1023;
          long long idx = (((long long)(b * HH + h) * SS + s) << 6) + d;
          if (c == 0) {
            __hip_bfloat16 hh = __float2bfloat16(v);
            o1[idx] = hh;
            o2[idx] = __float2bfloat16(v - __bfloat162float(hh));
          } else if (c == 1) {
            __hip_bfloat16 hh = __float2bfloat16(v);
            o3[idx] = hh;
            o4[idx] = __float2bfloat16(v - __bfloat162float(hh));
          } else {
            o5[(((long long)(b * HH + h) * DD + d) << 10) + s] = __float2bfloat16(v);
          }
        } else if (MODE == 1) {
          oF[zz * (SS * SS) + (long long)m * SS + n] = v * 0.125f;
        } else if (MODE == 2) {
          if (n < DD) {
            int b = (int)(zz >> 4), h = (int)(zz & 15);
            o1[(((long long)(b * SS + m)) << 10) + h * DD + n] = __float2bfloat16(v);
          }
        } else {
          oF[(long long)m * EE + n] = v + bias[n];
        }
      }
    }
  }
}

// ---------------------------------------------------------------------------
// fp32 softmax + threshold filter + renormalize, in place. One wave per row.
// m=max(l); e=exp(l-m); Z=sum e; sel = e/Z > 4e-4; out = sel ? e/sum(sel e):0.
// Row max always selected (1/Z >= 1/1024 > 4e-4) => Zs >= 1, no NaN possible.
// ---------------------------------------------------------------------------
__device__ __forceinline__ float wave_max64(float v) {
#pragma unroll
  for (int o = 32; o > 0; o >>= 1) v = fmaxf(v, __shfl_xor(v, o));
  return v;
}
__device__ __forceinline__ float wave_sum64(float v) {
#pragma unroll
  for (int o = 32; o > 0; o >>= 1) v += __shfl_xor(v, o);
  return v;
}

__global__ __launch_bounds__(256) void softmax_filter(float* __restrict__ attn) {
  const int lane = threadIdx.x & 63;
  const long long row = (long long)blockIdx.x * 4 + (threadIdx.x >> 6);
  float* p = attn + (row << 10);

  float4 raw[4];
#pragma unroll
  for (int i = 0; i < 4; ++i) raw[i] = ((const float4*)p)[i * 64 + lane];
  float v[16];
#pragma unroll
  for (int i = 0; i < 4; ++i) {
    v[i * 4 + 0] = raw[i].x; v[i * 4 + 1] = raw[i].y;
    v[i * 4 + 2] = raw[i].z; v[i * 4 + 3] = raw[i].w;
  }

  float mloc = v[0];
#pragma unroll
  for (int t = 1; t < 16; ++t) mloc = fmaxf(mloc, v[t]);
  const float m = wave_max64(mloc);

  float e[16], zloc = 0.f;
#pragma unroll
  for (int t = 0; t < 16; ++t) { e[t] = expf(v[t] - m); zloc += e[t]; }
  const float Z = wave_sum64(zloc);

  float zsloc = 0.f;
  bool sel[16];
#pragma unroll
  for (int t = 0; t < 16; ++t) {
    sel[t] = (e[t] / Z) > 4e-4f;
    if (sel[t]) zsloc += e[t];
  }
  const float Zs = wave_sum64(zsloc);

#pragma unroll
  for (int i = 0; i < 4; ++i) {
    float4 w;
    w.x = sel[i * 4 + 0] ? e[i * 4 + 0] / Zs : 0.f;
    w.y = sel[i * 4 + 1] ? e[i * 4 + 1] / Zs : 0.f;
    w.z = sel[i * 4 + 2] ? e[i * 4 + 2] / Zs : 0.f;
    w.w = sel[i * 4 + 3] ? e[i * 4 + 3] / Zs : 0.f;
    ((float4*)p)[i * 64 + lane] = w;
  }
}

// ---------------------------------------------------------------------------
extern "C" void kernel_launch(void* const* d_in, const int* in_sizes, int n_in,
                              void* d_out, int out_size, void* d_ws, size_t ws_size,
                              hipStream_t stream) {
  const float* x     = (const float*)d_in[0];  // [4,1024,1024]
  const float* Wqkv  = (const float*)d_in[1];  // [3072,1024]
  const float* bqkv  = (const float*)d_in[2];  // [3072]
  const float* Wproj = (const float*)d_in[3];  // [1024,1024]
  const float* bproj = (const float*)d_in[4];  // [1024]

  float* out   = (float*)d_out;                        // 4M floats
  float* attnF = out + (size_t)BB * SS * EE;           // 64M floats

  const size_t M1 = 1024 * 1024;
  __hip_bfloat16* w = (__hip_bfloat16*)d_ws;

  if (ws_size >= (size_t)80 * 1024 * 1024) {
    // flat: 39M bf16 elems = 78MB
    __hip_bfloat16 *xh = w, *xl = xh + 4 * M1;
    __hip_bfloat16 *Wqh = xl + 4 * M1, *Wql = Wqh + 3 * M1, *Wph = Wql + 3 * M1;
    __hip_bfloat16 *qh = Wph + M1, *ql = qh + 4 * M1, *kh = ql + 4 * M1, *kl = kh + 4 * M1;
    __hip_bfloat16 *vT = kl + 4 * M1, *ao = vT + 4 * M1;

    split_f32<<<4096, 256, 0, stream>>>(x, xh, xl, 1024 * 1024);
    split_f32<<<3072, 256, 0, stream>>>(Wqkv, Wqh, Wql, 768 * 1024);
    split_f32<<<1024, 256, 0, stream>>>(Wproj, Wph, nullptr, 256 * 1024);

    gemm<0><<<dim3(24, 32, 1), 256, 0, stream>>>(
        xh, xl, Wqh, Wql, nullptr, bqkv, nullptr, qh, ql, kh, kl, vT,
        4096, 3072, 1024, 1024, 1024, 0LL, 0LL);
    gemm<1><<<dim3(8, 8, 64), 256, 0, stream>>>(
        qh, ql, kh, kl, nullptr, nullptr, attnF, nullptr, nullptr, nullptr, nullptr, nullptr,
        1024, 1024, 64, 64, 64, (long long)(SS * DD), (long long)(SS * DD));
    softmax_filter<<<dim3(65536 / 4), 256, 0, stream>>>(attnF);
    gemm<2><<<dim3(1, 8, 64), 256, 0, stream>>>(
        nullptr, nullptr, vT, nullptr, attnF, nullptr, nullptr, ao, nullptr, nullptr, nullptr, nullptr,
        1024, 64, 1024, 1024, 1024, (long long)(SS * SS), (long long)(DD * SS));
    gemm<3><<<dim3(8, 32, 1), 256, 0, stream>>>(
        ao, nullptr, Wph, nullptr, nullptr, bproj, out, nullptr, nullptr, nullptr, nullptr, nullptr,
        4096, 1024, 1024, 1024, 1024, 0LL, 0LL);
    return;
  }

  // per-batch: 7M shared + 8M per-batch = 15M elems = 30MB
  __hip_bfloat16 *Wqh = w, *Wql = Wqh + 3 * M1, *Wph = Wql + 3 * M1;
  __hip_bfloat16 *xh = Wph + M1, *xl = xh + M1;
  __hip_bfloat16 *qh = xl + M1, *ql = qh + M1, *kh = ql + M1, *kl = kh + M1;
  __hip_bfloat16 *vT = kl + M1, *ao = vT + M1;

  split_f32<<<3072, 256, 0, stream>>>(Wqkv, Wqh, Wql, 768 * 1024);
  split_f32<<<1024, 256, 0, stream>>>(Wproj, Wph, nullptr, 256 * 1024);

  for (int b = 0; b < BB; ++b) {
    const float* xb   = x + (size_t)b * SS * EE;
    float* attnb      = attnF + (size_t)b * HH * SS * SS;
    float* outb       = out + (size_t)b * SS * EE;

    split_f32<<<1024, 256, 0, stream>>>(xb, xh, xl, 256 * 1024);
    gemm<0><<<dim3(24, 8, 1), 256, 0, stream>>>(
        xh, xl, Wqh, Wql, nullptr, bqkv, nullptr, qh, ql, kh, kl, vT,
        1024, 3072, 1024, 1024, 1024, 0LL, 0LL);
    gemm<1><<<dim3(8, 8, 16), 256, 0, stream>>>(
        qh, ql, kh, kl, nullptr, nullptr, attnb, nullptr, nullptr, nullptr, nullptr, nullptr,
        1024, 1024, 64, 64, 64, (long long)(SS * DD), (long long)(SS * DD));
    softmax_filter<<<dim3(16384 / 4), 256, 0, stream>>>(attnb);
    gemm<2><<<dim3(1, 8, 16), 256, 0, stream>>>(
        nullptr, nullptr, vT, nullptr, attnb, nullptr, nullptr, ao, nullptr, nullptr, nullptr, nullptr,
        1024, 64, 1024, 1024, 1024, (long long)(SS * SS), (long long)(DD * SS));
    gemm<3><<<dim3(8, 8, 1), 256, 0, stream>>>(
        ao, nullptr, Wph, nullptr, nullptr, bproj, outb, nullptr, nullptr, nullptr, nullptr, nullptr,
        1024, 1024, 1024, 1024, 1024, 0LL, 0LL);
  }
}